// Round 7
// baseline (220.778 us; speedup 1.0000x reference)
//
#include <hip/hip_runtime.h>
#include <hip/hip_bf16.h>

// GraphConvolution: out = (adj_agg o (X @ W)) + bias  restructured as
//   out = X @ W' + bias,  W'[k,r] = sum_{e: rows[e]==r} vals[e] * W[k, cols[e]]
// (aggregation acts on W's column dim -> commutes with the GEMM).
// N=2048, D_IN=1024, D_OUT=8192, E=131072.
//
// R7: GEMM A-operand moved out of LDS -> direct global fragment loads.
// R6 accounting: LDS pipe (192 KB rd + 64 KB wr per K-tile per CU ~ 2800cy)
// oversubscribed vs MFMA (2483cy); 3x read amplification (A rd by 4 waves,
// B by 2) is structural.  A is 4 MB (L2/L3-resident) and its MFMA fragment
// layout = per-lane 16B at 64B/row granularity == CDNA 64B lines -> direct
// global loads with L1 catching the 4-way wave redundancy.  LDS now holds
// B only (2x32KB dbuf): 64KB rd + 32KB wr ~ 1030cy << MFMA -> MFMA-bound.
// fused_pre / aggregate_slices unchanged (controls).

#define N_ROWS 2048
#define D_IN   1024
#define D_OUT  8192
#define SLOT_SHIFT 6              // 64 slots/row; Poisson(16) max-degree safe
#define SLOTS (1 << SLOT_SHIFT)

typedef __attribute__((ext_vector_type(8))) short bf16x8;
typedef __attribute__((ext_vector_type(4))) float f32x4;
typedef __attribute__((ext_vector_type(2))) float f32x2;

__device__ __forceinline__ float bf2f(unsigned short u) {
    union { unsigned int i; float f; } x; x.i = ((unsigned int)u) << 16; return x.f;
}
__device__ __forceinline__ unsigned short f2bf(float f) {
    union { unsigned int i; float f; } x; x.f = f;
    unsigned int r = x.i + 0x7FFFu + ((x.i >> 16) & 1u);   // round-nearest-even
    return (unsigned short)(r >> 16);
}

// async global->LDS, 16B per lane; LDS dest = wave-uniform base + lane*16
__device__ __forceinline__ void async_load16(const void* g, void* l) {
    __builtin_amdgcn_global_load_lds(
        (const __attribute__((address_space(1))) void*)g,
        (__attribute__((address_space(3))) void*)l,
        16, 0, 0);
}

// ---------------- stage 1 (fused): W-transpose+convert | X-convert | fill --
__global__ __launch_bounds__(256) void fused_pre(
    const float* __restrict__ w, unsigned short* __restrict__ wt,
    const float* __restrict__ in, unsigned short* __restrict__ xout,
    const int* __restrict__ rows, const int* __restrict__ cols,
    const float* __restrict__ vals,
    int* __restrict__ cursors, int2* __restrict__ csr_cv, int E)
{
    __shared__ float tile[64][65];
    const int b = blockIdx.x;
    const int t = threadIdx.x;

    if (b < 2048) {
        // ---- W [D_IN, D_OUT] f32 -> W^T [D_OUT, D_IN] bf16, 64x64 tile
        const int bx = b & 127;          // D_OUT/64 = 128
        const int by = b >> 7;           // D_IN/64  = 16
        #pragma unroll
        for (int pass = 0; pass < 4; ++pass) {
            const int item = pass * 256 + t;
            const int r  = item >> 4;        // 0..63
            const int c4 = item & 15;        // 0..15
            const float4 v = *(const float4*)&w[(size_t)(by * 64 + r) * D_OUT + bx * 64 + c4 * 4];
            tile[r][c4 * 4 + 0] = v.x; tile[r][c4 * 4 + 1] = v.y;
            tile[r][c4 * 4 + 2] = v.z; tile[r][c4 * 4 + 3] = v.w;
        }
        __syncthreads();
        #pragma unroll
        for (int pass = 0; pass < 4; ++pass) {
            const int item = pass * 256 + t;
            const int rr  = item >> 4;       // 0..63 out-row within tile
            const int cc4 = item & 15;       // 0..15
            ushort4 o;
            o.x = f2bf(tile[cc4 * 4 + 0][rr]);
            o.y = f2bf(tile[cc4 * 4 + 1][rr]);
            o.z = f2bf(tile[cc4 * 4 + 2][rr]);
            o.w = f2bf(tile[cc4 * 4 + 3][rr]);
            *(ushort4*)&wt[(size_t)(bx * 64 + rr) * D_IN + by * 64 + cc4 * 4] = o;
        }
    } else if (b < 4096) {
        // ---- X f32 -> bf16 (8 MB read, 4 MB write)
        const int i = ((b - 2048) * 256 + t) * 4;     // sizes divide exactly
        const float4 v = *(const float4*)(in + i);
        ushort4 o; o.x = f2bf(v.x); o.y = f2bf(v.y); o.z = f2bf(v.z); o.w = f2bf(v.w);
        *(ushort4*)(xout + i) = o;
    } else {
        // ---- edge scatter into fixed-stride buckets
        const int e = (b - 4096) * 256 + t;
        if (e < E) {
            const int r = rows[e];
            const int pos = atomicAdd(&cursors[r], 1);
            if (pos < SLOTS) {               // memory-safety guard (never hit)
                int2 cv; cv.x = cols[e]; cv.y = __float_as_int(vals[e]);
                csr_cv[(r << SLOT_SHIFT) + pos] = cv;
            }
        }
    }
}

// ---------------- stage 2: W'^T[r,:] = sum vals[e] * W^T[cols[e],:] ---------
// XCD-L2-sliced gather (unchanged, R6-verified): k split into 8 slices of
// 2 MB; slice = blockIdx&7 keeps each slice on one XCD's L2 (heuristic).
__global__ __launch_bounds__(256, 8) void aggregate_slices(
    const unsigned short* __restrict__ wtb,   // W^T [D_OUT, D_IN] bf16
    const int* __restrict__ cnts,             // per-row edge counts (cursors)
    const int2* __restrict__ csr_cv,
    unsigned short* __restrict__ wpt)         // W'^T [D_OUT, D_IN] bf16
{
    const int wave  = threadIdx.x >> 6;              // 0..3
    const int lane  = threadIdx.x & 63;
    const int slice = blockIdx.x & 7;                // -> XCD (heuristic)
    const int r     = (blockIdx.x >> 3) * 4 + wave;  // 0..8191
    const int k0    = slice * 128 + lane * 2;        // element offset

    const int beg = r << SLOT_SHIFT;
    int cnt = cnts[r]; if (cnt > SLOTS) cnt = SLOTS;
    const int end = beg + cnt;

    const unsigned short* wb = wtb + k0;
    f32x2 acc = (f32x2){0.f, 0.f};

    int i = beg;
    for (; i + 4 <= end; i += 4) {
        int2 cv[4]; unsigned int g[4];
        #pragma unroll
        for (int j = 0; j < 4; ++j) cv[j] = csr_cv[i + j];
        #pragma unroll
        for (int j = 0; j < 4; ++j)
            g[j] = *(const unsigned int*)(wb + (size_t)cv[j].x * D_IN);
        #pragma unroll
        for (int j = 0; j < 4; ++j) {
            const float v = __int_as_float(cv[j].y);
            union { unsigned int i; float f; } lo, hi;
            lo.i = g[j] << 16; hi.i = g[j] & 0xffff0000u;
            acc += (f32x2){v, v} * (f32x2){lo.f, hi.f};
        }
    }
    for (; i < end; ++i) {
        const int2 cv = csr_cv[i];
        const float v = __int_as_float(cv.y);
        const unsigned int g = *(const unsigned int*)(wb + (size_t)cv.x * D_IN);
        union { unsigned int i; float f; } lo, hi;
        lo.i = g << 16; hi.i = g & 0xffff0000u;
        acc += (f32x2){v, v} * (f32x2){lo.f, hi.f};
    }

    const unsigned int o = (unsigned int)f2bf(acc[0]) | ((unsigned int)f2bf(acc[1]) << 16);
    *(unsigned int*)(wpt + (size_t)r * D_IN + k0) = o;
}

// ---------------- stage 3: C = A @ B^T + bias -------------------------------
// 256x256 tile, BK=64, 8 waves (2Mx4N).  B: LDS double-buffer 2x32KB with
// the verified XOR-chunk swizzle + global_load_lds DMA.  A: direct global
// fragment loads (per-lane 16B, 64B/row granularity, L1/L2-served; no LDS,
// no barrier dependence).  Fragment register pipelining retained: phase p
// issues quadrant-(p+1) A-loads (vmcnt-tracked) and computes quadrant p.
// One {vmcnt(0) lgkmcnt(0); s_barrier} per K-tile at the B buffer flip.
struct QuadFrags { bf16x8 a00, a01, a10, a11; };

// A-frag global loads: aK = A + (br*256 + wr*128 + l16)*1024 + q*8 + kt*64
// quadrant MI0 covers rows +MI0*16 .. +MI0*16+31 (2 MFMA row-tiles)
#define READQ_G(Q, AK, MI0)                                                     \
    (Q).a00 = *(const bf16x8*)((AK) + (MI0)     * 16384);                       \
    (Q).a01 = *(const bf16x8*)((AK) + (MI0)     * 16384 + 32);                  \
    (Q).a10 = *(const bf16x8*)((AK) + (MI0 + 1) * 16384);                       \
    (Q).a11 = *(const bf16x8*)((AK) + (MI0 + 1) * 16384 + 32);

#define READ_BFR(BASE)                                                          \
    _Pragma("unroll")                                                           \
    for (int ni = 0; ni < 4; ++ni) {                                            \
        bfr[0][ni] = *(const bf16x8*)((BASE) + rowB + ni * 1024 + x0 * 8);      \
        bfr[1][ni] = *(const bf16x8*)((BASE) + rowB + ni * 1024 + x1 * 8);      \
    }

#define MFMA_Q(Q, MI0)                                                          \
    __builtin_amdgcn_s_setprio(1);                                              \
    _Pragma("unroll")                                                           \
    for (int ni = 0; ni < 4; ++ni)                                              \
        acc[MI0][ni]     = __builtin_amdgcn_mfma_f32_16x16x32_bf16(             \
            (Q).a00, bfr[0][ni], acc[MI0][ni], 0, 0, 0);                        \
    _Pragma("unroll")                                                           \
    for (int ni = 0; ni < 4; ++ni)                                              \
        acc[MI0 + 1][ni] = __builtin_amdgcn_mfma_f32_16x16x32_bf16(             \
            (Q).a10, bfr[0][ni], acc[MI0 + 1][ni], 0, 0, 0);                    \
    _Pragma("unroll")                                                           \
    for (int ni = 0; ni < 4; ++ni)                                              \
        acc[MI0][ni]     = __builtin_amdgcn_mfma_f32_16x16x32_bf16(             \
            (Q).a01, bfr[1][ni], acc[MI0][ni], 0, 0, 0);                        \
    _Pragma("unroll")                                                           \
    for (int ni = 0; ni < 4; ++ni)                                              \
        acc[MI0 + 1][ni] = __builtin_amdgcn_mfma_f32_16x16x32_bf16(             \
            (Q).a11, bfr[1][ni], acc[MI0 + 1][ni], 0, 0, 0);                    \
    __builtin_amdgcn_s_setprio(0);

__global__ __launch_bounds__(512, 2) void gemm_bt_bias(
    const unsigned short* __restrict__ A,     // [N_ROWS, D_IN] bf16
    const unsigned short* __restrict__ B,     // [D_OUT, D_IN] bf16 (= W'^T)
    const float*  __restrict__ bias,
    float* __restrict__ C)
{
    // B only: [buf][256 rows][64 k] bf16 = 2 x 32 KB
    __shared__ unsigned short lds[32768];

    const int tid  = threadIdx.x;             // 0..511
    const int wave = tid >> 6;                // 0..7
    const int lane = tid & 63;
    const int q    = lane >> 4;               // 0..3
    const int l16  = lane & 15;               // 0..15
    const int wr   = wave >> 2;               // 0..1  (A half: rows wr*128..)
    const int wc   = wave & 3;                // 0..3  (B quarter: rows wc*64..)

    const int bc = blockIdx.x;                // 0..31  col-chunk of C
    const int br = blockIdx.y;                // 0..7   row-chunk of C

    // ---- B staging geometry: thread t covers LDS chunk (tid) per 8KB round
    const int srow = tid >> 3;                       // 0..63 row within round
    const int lc   = (tid & 7) ^ (srow & 7);         // inverse-swizzled source chunk
    const char* Bsrc = (const char*)B + ((size_t)(bc * 256) + srow) * (D_IN * 2) + lc * 16;
    char* ldsc = (char*)lds;

    // ---- B fragment-read geometry (LDS, swizzled); row&7 == l16&7
    const int x0   = q ^ (l16 & 7);                  // phys chunk, k-step 0
    const int x1   = x0 ^ 4;                         // phys chunk, k-step 1
    const int rowB = (wc * 64 + l16) * 64;

    // ---- A fragment-read geometry (global, per-lane)
    const unsigned short* aA =
        A + (size_t)(br * 256 + wr * 128 + l16) * D_IN + q * 8;

    f32x4 acc[8][4];
    #pragma unroll
    for (int i = 0; i < 8; ++i)
        #pragma unroll
        for (int j = 0; j < 4; ++j)
            acc[i][j] = (f32x4){0.f, 0.f, 0.f, 0.f};

    // ---- prologue: stage B K-tile 0 into buffer 0
    #pragma unroll
    for (int j = 0; j < 4; ++j)
        async_load16(Bsrc + (size_t)j * 64 * (D_IN * 2), ldsc + j * 8192 + tid * 16);

    asm volatile("s_waitcnt vmcnt(0)" ::: "memory");
    __builtin_amdgcn_s_barrier();

    QuadFrags RA, RB;
    bf16x8 bfr[2][4];
    {   // pre-read tile-0 B-frags (LDS) + quadrant 0 A-frags (global)
        READ_BFR(lds)
        READQ_G(RA, aA, 0)
    }

    for (int kt = 0; kt < D_IN / 64; ++kt) {
        const int cur = kt & 1;
        const unsigned short* Bb = lds + cur * 16384;
        char* dstB = ldsc + (cur ^ 1) * 32768 + tid * 16;
        const char* srcB = Bsrc + (size_t)(kt + 1) * 128;
        const unsigned short* aK = aA + kt * 64;     // this tile's A k-base
        const bool pf = (kt + 1 < D_IN / 64);

        // ---- phase 0: issue B-DMAs(kt+1); issue A quad1; compute quad0
        if (pf) {
            async_load16(srcB,                            dstB);
            async_load16(srcB + (size_t)64  * (D_IN * 2), dstB + 8192);
            async_load16(srcB + (size_t)128 * (D_IN * 2), dstB + 16384);
            async_load16(srcB + (size_t)192 * (D_IN * 2), dstB + 24576);
        }
        READQ_G(RB, aK, 2)
        MFMA_Q(RA, 0)

        // ---- phase 1: issue A quad2; compute quad1
        READQ_G(RA, aK, 4)
        MFMA_Q(RB, 2)

        // ---- phase 2: issue A quad3; compute quad2
        READQ_G(RB, aK, 6)
        MFMA_Q(RA, 4)

        // ---- phase 3: boundary sync (own B-frag lgkm reads drained + all
        //      vmem landed: B-DMAs for buf^1 AND quad3 A-loads), barrier;
        //      then next tile's A quad0 (no barrier needed for A), compute
        //      quad3, then next tile's B-frags (old bfr consumed by program
        //      order -> no WAR).
        if (pf) {
            asm volatile("s_waitcnt vmcnt(0) lgkmcnt(0)" ::: "memory");
            __builtin_amdgcn_s_barrier();
            READQ_G(RA, aK + 64, 0)
            MFMA_Q(RB, 6)
            READ_BFR(lds + (cur ^ 1) * 16384)
        } else {
            MFMA_Q(RB, 6)
        }
    }

    // ---- epilogue: C/D layout col=lane&15, row=quad*4+reg (m89-verified)
    #pragma unroll
    for (int ni = 0; ni < 4; ++ni) {
        const int col = bc * 256 + wc * 64 + ni * 16 + l16;
        const float bv = bias[col];
        #pragma unroll
        for (int mi = 0; mi < 8; ++mi) {
            const int row0 = br * 256 + wr * 128 + mi * 16 + q * 4;
            #pragma unroll
            for (int r = 0; r < 4; ++r)
                C[(size_t)(row0 + r) * D_OUT + col] = acc[mi][ni][r] + bv;
        }
    }
}

extern "C" void kernel_launch(void* const* d_in, const int* in_sizes, int n_in,
                              void* d_out, int out_size, void* d_ws, size_t ws_size,
                              hipStream_t stream) {
    (void)n_in; (void)out_size; (void)ws_size;
    const float* input    = (const float*)d_in[0];   // [2048,1024]
    const float* weight   = (const float*)d_in[1];   // [1024,8192]
    const float* bias     = (const float*)d_in[2];   // [8192]
    const int*   adj_rows = (const int*)d_in[3];     // [E]
    const int*   adj_cols = (const int*)d_in[4];     // [E]
    const float* adj_vals = (const float*)d_in[5];   // [E]
    const int E = in_sizes[3];

    // workspace layout (~40 MB; ws re-poisoned each call, everything below
    // is fully rewritten or explicitly zeroed every launch)
    char* ws = (char*)d_ws;
    unsigned short* wtb = (unsigned short*)ws;                                // 16 MB  W^T bf16
    unsigned short* wpt = (unsigned short*)(ws + (size_t)16 * 1024 * 1024);   // 16 MB  W'^T bf16
    unsigned short* abf = (unsigned short*)(ws + (size_t)32 * 1024 * 1024);   //  4 MB  X bf16
    int*   cursors  = (int*)(ws + (size_t)36 * 1024 * 1024);                  // 32 KB
    int2*  csr_cv   = (int2*)(ws + (size_t)36 * 1024 * 1024 + 32 * 1024);     //  4 MB buckets

    const int fillBlocks = (E + 255) / 256;          // 512

    hipMemsetAsync(cursors, 0, D_OUT * sizeof(int), stream);
    fused_pre<<<4096 + fillBlocks, 256, 0, stream>>>(
        weight, wtb, input, abf, adj_rows, adj_cols, adj_vals,
        cursors, csr_cv, E);
    aggregate_slices<<<(D_OUT / 4) * 8, 256, 0, stream>>>(
        wtb, cursors, csr_cv, wpt);
    gemm_bt_bias<<<dim3(D_OUT / 256, N_ROWS / 256), 512, 0, stream>>>(
        abf, wpt, bias, (float*)d_out);
}

// Round 8
// 183.230 us; speedup vs baseline: 1.2049x; 1.2049x over previous
//
#include <hip/hip_runtime.h>
#include <hip/hip_bf16.h>

// GraphConvolution: out = (adj_agg o (X @ W)) + bias  restructured as
//   out = X @ W' + bias,  W'[k,r] = sum_{e: rows[e]==r} vals[e] * W[k, cols[e]]
// (aggregation acts on W's column dim -> commutes with the GEMM).
// N=2048, D_IN=1024, D_OUT=8192, E=131072.
//
// R8: R7's global-A falsified (82us, MfmaUtil 15.5) -> A back in LDS.
// GEMM rebuilt around T4 (counted vmcnt, the one catalog lever never
// actually implemented here): BK=32, TRIPLE-buffered LDS (3x32KB), DMAs
// issued 2 tiles ahead, boundary wait vmcnt(4) (newer tile stays in
// flight) instead of vmcnt(0).  R6 measurement: per-K-tile = MFMA(2483cy)
// + LDS(2340cy) fully serialized (4950cy measured); m201 proves the same
// traffic can run at ~3300cy on this chip -> the boundary drain is the
// candidate gap.  fused_pre / aggregate_slices unchanged (controls).

#define N_ROWS 2048
#define D_IN   1024
#define D_OUT  8192
#define SLOT_SHIFT 6              // 64 slots/row; Poisson(16) max-degree safe
#define SLOTS (1 << SLOT_SHIFT)

typedef __attribute__((ext_vector_type(8))) short bf16x8;
typedef __attribute__((ext_vector_type(4))) float f32x4;
typedef __attribute__((ext_vector_type(2))) float f32x2;

__device__ __forceinline__ float bf2f(unsigned short u) {
    union { unsigned int i; float f; } x; x.i = ((unsigned int)u) << 16; return x.f;
}
__device__ __forceinline__ unsigned short f2bf(float f) {
    union { unsigned int i; float f; } x; x.f = f;
    unsigned int r = x.i + 0x7FFFu + ((x.i >> 16) & 1u);   // round-nearest-even
    return (unsigned short)(r >> 16);
}

// async global->LDS, 16B per lane; LDS dest = wave-uniform base + lane*16
__device__ __forceinline__ void async_load16(const void* g, void* l) {
    __builtin_amdgcn_global_load_lds(
        (const __attribute__((address_space(1))) void*)g,
        (__attribute__((address_space(3))) void*)l,
        16, 0, 0);
}

// ---------------- stage 1 (fused): W-transpose+convert | X-convert | fill --
__global__ __launch_bounds__(256) void fused_pre(
    const float* __restrict__ w, unsigned short* __restrict__ wt,
    const float* __restrict__ in, unsigned short* __restrict__ xout,
    const int* __restrict__ rows, const int* __restrict__ cols,
    const float* __restrict__ vals,
    int* __restrict__ cursors, int2* __restrict__ csr_cv, int E)
{
    __shared__ float tile[64][65];
    const int b = blockIdx.x;
    const int t = threadIdx.x;

    if (b < 2048) {
        // ---- W [D_IN, D_OUT] f32 -> W^T [D_OUT, D_IN] bf16, 64x64 tile
        const int bx = b & 127;          // D_OUT/64 = 128
        const int by = b >> 7;           // D_IN/64  = 16
        #pragma unroll
        for (int pass = 0; pass < 4; ++pass) {
            const int item = pass * 256 + t;
            const int r  = item >> 4;        // 0..63
            const int c4 = item & 15;        // 0..15
            const float4 v = *(const float4*)&w[(size_t)(by * 64 + r) * D_OUT + bx * 64 + c4 * 4];
            tile[r][c4 * 4 + 0] = v.x; tile[r][c4 * 4 + 1] = v.y;
            tile[r][c4 * 4 + 2] = v.z; tile[r][c4 * 4 + 3] = v.w;
        }
        __syncthreads();
        #pragma unroll
        for (int pass = 0; pass < 4; ++pass) {
            const int item = pass * 256 + t;
            const int rr  = item >> 4;       // 0..63 out-row within tile
            const int cc4 = item & 15;       // 0..15
            ushort4 o;
            o.x = f2bf(tile[cc4 * 4 + 0][rr]);
            o.y = f2bf(tile[cc4 * 4 + 1][rr]);
            o.z = f2bf(tile[cc4 * 4 + 2][rr]);
            o.w = f2bf(tile[cc4 * 4 + 3][rr]);
            *(ushort4*)&wt[(size_t)(bx * 64 + rr) * D_IN + by * 64 + cc4 * 4] = o;
        }
    } else if (b < 4096) {
        // ---- X f32 -> bf16 (8 MB read, 4 MB write)
        const int i = ((b - 2048) * 256 + t) * 4;     // sizes divide exactly
        const float4 v = *(const float4*)(in + i);
        ushort4 o; o.x = f2bf(v.x); o.y = f2bf(v.y); o.z = f2bf(v.z); o.w = f2bf(v.w);
        *(ushort4*)(xout + i) = o;
    } else {
        // ---- edge scatter into fixed-stride buckets
        const int e = (b - 4096) * 256 + t;
        if (e < E) {
            const int r = rows[e];
            const int pos = atomicAdd(&cursors[r], 1);
            if (pos < SLOTS) {               // memory-safety guard (never hit)
                int2 cv; cv.x = cols[e]; cv.y = __float_as_int(vals[e]);
                csr_cv[(r << SLOT_SHIFT) + pos] = cv;
            }
        }
    }
}

// ---------------- stage 2: W'^T[r,:] = sum vals[e] * W^T[cols[e],:] ---------
// XCD-L2-sliced gather (unchanged, R6-verified): k split into 8 slices of
// 2 MB; slice = blockIdx&7 keeps each slice on one XCD's L2 (heuristic).
__global__ __launch_bounds__(256, 8) void aggregate_slices(
    const unsigned short* __restrict__ wtb,   // W^T [D_OUT, D_IN] bf16
    const int* __restrict__ cnts,             // per-row edge counts (cursors)
    const int2* __restrict__ csr_cv,
    unsigned short* __restrict__ wpt)         // W'^T [D_OUT, D_IN] bf16
{
    const int wave  = threadIdx.x >> 6;              // 0..3
    const int lane  = threadIdx.x & 63;
    const int slice = blockIdx.x & 7;                // -> XCD (heuristic)
    const int r     = (blockIdx.x >> 3) * 4 + wave;  // 0..8191
    const int k0    = slice * 128 + lane * 2;        // element offset

    const int beg = r << SLOT_SHIFT;
    int cnt = cnts[r]; if (cnt > SLOTS) cnt = SLOTS;
    const int end = beg + cnt;

    const unsigned short* wb = wtb + k0;
    f32x2 acc = (f32x2){0.f, 0.f};

    int i = beg;
    for (; i + 4 <= end; i += 4) {
        int2 cv[4]; unsigned int g[4];
        #pragma unroll
        for (int j = 0; j < 4; ++j) cv[j] = csr_cv[i + j];
        #pragma unroll
        for (int j = 0; j < 4; ++j)
            g[j] = *(const unsigned int*)(wb + (size_t)cv[j].x * D_IN);
        #pragma unroll
        for (int j = 0; j < 4; ++j) {
            const float v = __int_as_float(cv[j].y);
            union { unsigned int i; float f; } lo, hi;
            lo.i = g[j] << 16; hi.i = g[j] & 0xffff0000u;
            acc += (f32x2){v, v} * (f32x2){lo.f, hi.f};
        }
    }
    for (; i < end; ++i) {
        const int2 cv = csr_cv[i];
        const float v = __int_as_float(cv.y);
        const unsigned int g = *(const unsigned int*)(wb + (size_t)cv.x * D_IN);
        union { unsigned int i; float f; } lo, hi;
        lo.i = g << 16; hi.i = g & 0xffff0000u;
        acc += (f32x2){v, v} * (f32x2){lo.f, hi.f};
    }

    const unsigned int o = (unsigned int)f2bf(acc[0]) | ((unsigned int)f2bf(acc[1]) << 16);
    *(unsigned int*)(wpt + (size_t)r * D_IN + k0) = o;
}

// ---------------- stage 3: C = A @ B^T + bias -------------------------------
// 256x256 tile, BK=32 (32 K-tiles), 8 waves (2Mx4N), TRIPLE-buffered LDS:
// 3 bufs x (A 16KB + B 16KB) = 96KB.  Iteration t: {vmcnt(4) lgkm(0);
// barrier; STAGE(t+2); ds_read 12 frags from buf[t%3]; 32 MFMA}.  DMAs for
// tile t land with ~2 tiles (~4000cy) of slack; boundary vmcnt(4) keeps
// tile t+1's 4 DMAs in flight (T4 counted-vmcnt; never drain to 0 in the
// main loop).  LDS rows are 64B (4 chunks of 16B); chunk c of row r at
// phys chunk c ^ (r&3); linear DMA dest + inverse-swizzled global source
// (rule #21); balanced 8 lanes per 4-bank group by construction.
__global__ __launch_bounds__(512, 2) void gemm_bt_bias(
    const unsigned short* __restrict__ A,     // [N_ROWS, D_IN] bf16
    const unsigned short* __restrict__ B,     // [D_OUT, D_IN] bf16 (= W'^T)
    const float*  __restrict__ bias,
    float* __restrict__ C)
{
    __shared__ unsigned short lds[49152];     // 96 KB

    const int tid  = threadIdx.x;             // 0..511
    const int wave = tid >> 6;                // 0..7
    const int lane = tid & 63;
    const int q    = lane >> 4;               // 0..3
    const int l16  = lane & 15;               // 0..15
    const int wr   = wave >> 2;               // 0..1  (A half: rows wr*128..)
    const int wc   = wave & 3;                // 0..3  (B quarter: rows wc*64..)

    const int bc = blockIdx.x;                // 0..31  col-chunk of C
    const int br = blockIdx.y;                // 0..7   row-chunk of C

    // ---- staging geometry: instr j covers rows j*128..j*128+127; thread t
    //      -> row j*128 + (t>>2), phys chunk t&3, source chunk inverse-swz
    const int srow = tid >> 2;                       // 0..127
    const int lc   = (tid & 3) ^ (srow & 3);         // inverse-swizzled source chunk
    const char* Asrc = (const char*)A + ((size_t)(br * 256) + srow) * (D_IN * 2) + lc * 16;
    const char* Bsrc = (const char*)B + ((size_t)(bc * 256) + srow) * (D_IN * 2) + lc * 16;
    char* ldsc = (char*)lds;

    // ---- fragment-read geometry (shorts); row stride 32 shorts (64B)
    const int xc   = (q ^ (l16 & 3)) * 8;            // phys chunk short-offset
    const int rowA = (wr * 128 + l16) * 32;          // + mi*512
    const int rowB = (wc * 64  + l16) * 32;          // + ni*512

    f32x4 acc[8][4];
    #pragma unroll
    for (int i = 0; i < 8; ++i)
        #pragma unroll
        for (int j = 0; j < 4; ++j)
            acc[i][j] = (f32x4){0.f, 0.f, 0.f, 0.f};

    // STAGE(T,BUF): 4 DMA instr/thread -> A rows 0..255, B rows 0..255 of
    // K-slice T (32 k = 64B per row) into buffer BUF (32KB: A 16K | B 16K).
    #define STAGE(T, BUF)                                                   \
    {   const size_t ko = (size_t)(T) * 64;                                 \
        char* d = ldsc + (BUF) * 32768 + tid * 16;                          \
        async_load16(Asrc + ko,                          d);                \
        async_load16(Asrc + (size_t)128 * (D_IN * 2) + ko, d + 8192);       \
        async_load16(Bsrc + ko,                          d + 16384);        \
        async_load16(Bsrc + (size_t)128 * (D_IN * 2) + ko, d + 24576);  }

    // ---- prologue: stage tiles 0 and 1
    STAGE(0, 0)
    STAGE(1, 1)

    int b0 = 0;                                      // t % 3
    for (int t = 0; t < 32; ++t) {
        // boundary: tile t's 4 DMAs landed (allow tile t+1's 4 in flight);
        // own reads drained; collective -> buf[t] ready, buf[t+2]%3 free.
        if (t < 31) asm volatile("s_waitcnt vmcnt(4) lgkmcnt(0)" ::: "memory");
        else        asm volatile("s_waitcnt vmcnt(0) lgkmcnt(0)" ::: "memory");
        __builtin_amdgcn_s_barrier();

        if (t + 2 < 32) {
            int b2 = b0 + 2; if (b2 >= 3) b2 -= 3;
            STAGE(t + 2, b2)
        }

        const unsigned short* Ab = lds + b0 * 16384;     // shorts
        const unsigned short* Bb = Ab + 8192;

        bf16x8 bfv[4], afv[8];
        #pragma unroll
        for (int ni = 0; ni < 4; ++ni)
            bfv[ni] = *(const bf16x8*)(Bb + rowB + ni * 512 + xc);
        #pragma unroll
        for (int mi = 0; mi < 8; ++mi)
            afv[mi] = *(const bf16x8*)(Ab + rowA + mi * 512 + xc);

        __builtin_amdgcn_s_setprio(1);
        #pragma unroll
        for (int mi = 0; mi < 8; ++mi)
            #pragma unroll
            for (int ni = 0; ni < 4; ++ni)
                acc[mi][ni] = __builtin_amdgcn_mfma_f32_16x16x32_bf16(
                    afv[mi], bfv[ni], acc[mi][ni], 0, 0, 0);
        __builtin_amdgcn_s_setprio(0);

        b0 = (b0 == 2) ? 0 : b0 + 1;
    }
    #undef STAGE

    // ---- epilogue: C/D layout col=lane&15, row=quad*4+reg (m89-verified)
    #pragma unroll
    for (int ni = 0; ni < 4; ++ni) {
        const int col = bc * 256 + wc * 64 + ni * 16 + l16;
        const float bv = bias[col];
        #pragma unroll
        for (int mi = 0; mi < 8; ++mi) {
            const int row0 = br * 256 + wr * 128 + mi * 16 + q * 4;
            #pragma unroll
            for (int r = 0; r < 4; ++r)
                C[(size_t)(row0 + r) * D_OUT + col] = acc[mi][ni][r] + bv;
        }
    }
}

extern "C" void kernel_launch(void* const* d_in, const int* in_sizes, int n_in,
                              void* d_out, int out_size, void* d_ws, size_t ws_size,
                              hipStream_t stream) {
    (void)n_in; (void)out_size; (void)ws_size;
    const float* input    = (const float*)d_in[0];   // [2048,1024]
    const float* weight   = (const float*)d_in[1];   // [1024,8192]
    const float* bias     = (const float*)d_in[2];   // [8192]
    const int*   adj_rows = (const int*)d_in[3];     // [E]
    const int*   adj_cols = (const int*)d_in[4];     // [E]
    const float* adj_vals = (const float*)d_in[5];   // [E]
    const int E = in_sizes[3];

    // workspace layout (~40 MB; ws re-poisoned each call, everything below
    // is fully rewritten or explicitly zeroed every launch)
    char* ws = (char*)d_ws;
    unsigned short* wtb = (unsigned short*)ws;                                // 16 MB  W^T bf16
    unsigned short* wpt = (unsigned short*)(ws + (size_t)16 * 1024 * 1024);   // 16 MB  W'^T bf16
    unsigned short* abf = (unsigned short*)(ws + (size_t)32 * 1024 * 1024);   //  4 MB  X bf16
    int*   cursors  = (int*)(ws + (size_t)36 * 1024 * 1024);                  // 32 KB
    int2*  csr_cv   = (int2*)(ws + (size_t)36 * 1024 * 1024 + 32 * 1024);     //  4 MB buckets

    const int fillBlocks = (E + 255) / 256;          // 512

    hipMemsetAsync(cursors, 0, D_OUT * sizeof(int), stream);
    fused_pre<<<4096 + fillBlocks, 256, 0, stream>>>(
        weight, wtb, input, abf, adj_rows, adj_cols, adj_vals,
        cursors, csr_cv, E);
    aggregate_slices<<<(D_OUT / 4) * 8, 256, 0, stream>>>(
        wtb, cursors, csr_cv, wpt);
    gemm_bt_bias<<<dim3(D_OUT / 256, N_ROWS / 256), 512, 0, stream>>>(
        abf, wpt, bias, (float*)d_out);
}